// Round 7
// baseline (149.226 us; speedup 1.0000x reference)
//
#include <hip/hip_runtime.h>
#include <hip/hip_bf16.h>

#define B_ 4
#define N_ 4096
#define L_ 4104
#define D_ 512
#define RT 17
#define JC2 32
#define CH2 129
#define BK 64

typedef __attribute__((ext_vector_type(8))) short bf16x8;
typedef __attribute__((ext_vector_type(4))) float f32x4;

__device__ __forceinline__ float bf2f(unsigned short u) {
  union { unsigned u; float f; } c; c.u = ((unsigned)u) << 16; return c.f;
}

// ---------------- K0: G_k = bf16(emb) @ bf16(W * cw_k)^T  (+ bias' on extra blocks) ----
// G[k][tok][o], tok<256, o<512.  32 MFMA blocks (2 m-tiles x 4 n-tiles x 4 taps) + 2 bias blocks.
__global__ __launch_bounds__(256) void k_g(const float* __restrict__ emb,
    const float* __restrict__ pw, const float* __restrict__ cwp,
    const float* __restrict__ cb, const float* __restrict__ pb,
    float* __restrict__ G, float* __restrict__ biasp) {
  const int bx = blockIdx.x;
  const int t = threadIdx.x;
  if (bx >= 32) {                        // bias'[o] = cb . W[o,:] + pb[o]
    const int o = (bx - 32) * 256 + t;
    const float4* wr = (const float4*)(pw + (size_t)o * 512);
    const float4* c4 = (const float4*)cb;
    float s = 0.f;
    for (int q = 0; q < 128; ++q) {
      const float4 a = wr[q], c = c4[q];
      s += a.x * c.x + a.y * c.y + a.z * c.z + a.w * c.w;
    }
    biasp[o] = s + pb[o];
    return;
  }
  __shared__ __align__(16) __hip_bfloat16 As[2][128 * BK];
  __shared__ __align__(16) __hip_bfloat16 Bs[2][128 * BK];
  const int m0 = (bx & 1) * 128;         // token tile
  const int n0 = ((bx >> 1) & 3) * 128;  // output-channel tile
  const int kp = bx >> 3;                // conv tap 0..3
  const int w = t >> 6, l = t & 63;
  const int quad = l >> 4, r16 = l & 15;
  const int wr_ = (w >> 1) * 64, wc = (w & 1) * 64;

  f32x4 acc[4][4];
#pragma unroll
  for (int a = 0; a < 4; ++a)
#pragma unroll
    for (int bq = 0; bq < 4; ++bq) acc[a][bq] = (f32x4){0.f, 0.f, 0.f, 0.f};

  // VALU staging: thread t handles row t>>1, granules (t&1)*4 .. +3 of the BK=64 chunk.
  // XOR granule swizzle (g ^ row&7) matches the fragment-read swizzle.
  const int srow = t >> 1;
  const int g0 = (t & 1) * 4;

#define STAGEG(buf, kb)                                                        \
  _Pragma("unroll")                                                            \
  for (int gi = 0; gi < 4; ++gi) {                                             \
    const int g = g0 + gi;                                                     \
    const int c0 = (kb) + g * 8;                                               \
    const float4 a0 = *(const float4*)(emb + (size_t)(m0 + srow) * 512 + c0);  \
    const float4 a1 = *(const float4*)(emb + (size_t)(m0 + srow) * 512 + c0 + 4);\
    const float4 b0 = *(const float4*)(pw + (size_t)(n0 + srow) * 512 + c0);   \
    const float4 b1 = *(const float4*)(pw + (size_t)(n0 + srow) * 512 + c0 + 4);\
    union { __hip_bfloat16 q[8]; bf16x8 v; } ua, ub;                           \
    ua.q[0] = __float2bfloat16(a0.x); ua.q[1] = __float2bfloat16(a0.y);        \
    ua.q[2] = __float2bfloat16(a0.z); ua.q[3] = __float2bfloat16(a0.w);        \
    ua.q[4] = __float2bfloat16(a1.x); ua.q[5] = __float2bfloat16(a1.y);        \
    ua.q[6] = __float2bfloat16(a1.z); ua.q[7] = __float2bfloat16(a1.w);        \
    float cwv[8];                                                              \
    _Pragma("unroll")                                                          \
    for (int e = 0; e < 8; ++e) cwv[e] = cwp[(c0 + e) * 4 + kp];               \
    ub.q[0] = __float2bfloat16(b0.x * cwv[0]); ub.q[1] = __float2bfloat16(b0.y * cwv[1]);\
    ub.q[2] = __float2bfloat16(b0.z * cwv[2]); ub.q[3] = __float2bfloat16(b0.w * cwv[3]);\
    ub.q[4] = __float2bfloat16(b1.x * cwv[4]); ub.q[5] = __float2bfloat16(b1.y * cwv[5]);\
    ub.q[6] = __float2bfloat16(b1.z * cwv[6]); ub.q[7] = __float2bfloat16(b1.w * cwv[7]);\
    const int dst = srow * BK + ((g ^ (srow & 7)) * 8);                        \
    *(bf16x8*)(&As[buf][dst]) = ua.v;                                          \
    *(bf16x8*)(&Bs[buf][dst]) = ub.v;                                          \
  }

  STAGEG(0, 0)
  __syncthreads();

#pragma unroll 1
  for (int kt = 0; kt < 8; ++kt) {
    const int cur = kt & 1;
    if (kt < 7) { STAGEG(1 - cur, (kt + 1) * BK) }
#pragma unroll
    for (int kk = 0; kk < 2; ++kk) {
      const int col_e = (kk * 32 + quad * 8) ^ ((r16 & 7) * 8);
      bf16x8 af[4], bfr[4];
#pragma unroll
      for (int ti = 0; ti < 4; ++ti)
        af[ti] = *(const bf16x8*)(&As[cur][(wr_ + ti * 16 + r16) * BK + col_e]);
#pragma unroll
      for (int tj = 0; tj < 4; ++tj)
        bfr[tj] = *(const bf16x8*)(&Bs[cur][(wc + tj * 16 + r16) * BK + col_e]);
#pragma unroll
      for (int ti = 0; ti < 4; ++ti)
#pragma unroll
        for (int tj = 0; tj < 4; ++tj)
          acc[ti][tj] = __builtin_amdgcn_mfma_f32_16x16x32_bf16(af[ti], bfr[tj], acc[ti][tj], 0, 0, 0);
    }
    __syncthreads();
  }
#undef STAGEG

#pragma unroll
  for (int ti = 0; ti < 4; ++ti) {
    const int gi0 = m0 + wr_ + ti * 16 + quad * 4;
#pragma unroll
    for (int tj = 0; tj < 4; ++tj) {
      const int go = n0 + wc + tj * 16 + r16;
#pragma unroll
      for (int r = 0; r < 4; ++r)
        G[((size_t)kp * 256 + gi0 + r) * 512 + go] = acc[ti][tj][r];
    }
  }
}

// ---------------- K1: h[i] = sum_k G_k[x[i+k]] + bias'  (bf16 out) + t = h . sw ----------
__global__ __launch_bounds__(256) void k_h(const int* __restrict__ x,
    const float* __restrict__ G, const float* __restrict__ biasp,
    const float* __restrict__ sw, unsigned* __restrict__ h,
    float* __restrict__ tb) {
  __shared__ int tokS[11];
  __shared__ float tpart[8][4];
  const int bx = blockIdx.x;             // 2048: b*512 + rowgroup
  const int b = bx >> 9, i0 = (bx & 511) * 8;
  const int t = threadIdx.x, d = t * 2, w = t >> 6, l = t & 63;
  if (t < 11) {
    const int j = i0 + t;
    tokS[t] = (j < N_) ? x[b * N_ + j] : 0;
  }
  __syncthreads();
  const float2 bp  = *(const float2*)(biasp + d);
  const float2 swv = *(const float2*)(sw + d);
#pragma unroll
  for (int r = 0; r < 8; ++r) {
    const int i = i0 + r;
    float2 acc = bp;
#pragma unroll
    for (int k = 0; k < 4; ++k) {
      if (i + k < N_) {
        const float2 g = *(const float2*)(G + ((size_t)k * 256 + tokS[r + k]) * 512 + d);
        acc.x += g.x; acc.y += g.y;
      }
    }
    union { __hip_bfloat16 q[2]; unsigned u; } pk;
    pk.q[0] = __float2bfloat16(acc.x);
    pk.q[1] = __float2bfloat16(acc.y);
    h[(size_t)(b * N_ + i) * 256 + t] = pk.u;
    float v = acc.x * swv.x + acc.y * swv.y;
#pragma unroll
    for (int off = 32; off > 0; off >>= 1) v += __shfl_xor(v, off);
    if (l == 0) tpart[r][w] = v;
  }
  __syncthreads();
  if (t < 8)
    tb[b * N_ + i0 + t] = tpart[t][0] + tpart[t][1] + tpart[t][2] + tpart[t][3];
}

// helper: 4-way softmax from a t-window in LDS
__device__ __forceinline__ float4 softmax4(const float* __restrict__ tw, int base,
                                           int i, float bb) {
  const float s0 = tw[i - base] + bb;
  const int j2 = i & ~1;
  const float s1 = (tw[j2 - base] + tw[j2 + 1 - base]) * 0.5f + bb;
  const int j3 = (i / 3) * 3;
  const float s2 = (tw[j3 - base] + tw[j3 + 1 - base] + tw[j3 + 2 - base]) * (1.f / 3.f) + bb;
  const int j4 = i & ~3;
  const float s3 = (tw[j4 - base] + tw[j4 + 1 - base] + tw[j4 + 2 - base] + tw[j4 + 3 - base]) * 0.25f + bb;
  const float m = fmaxf(fmaxf(s0, s1), fmaxf(s2, s3));
  const float e0 = __expf(s0 - m), e1 = __expf(s1 - m), e2 = __expf(s2 - m), e3 = __expf(s3 - m);
  const float inv = 1.f / (e0 + e1 + e2 + e3);
  return make_float4(e0 * inv, e1 * inv, e2 * inv, e3 * inv);
}

// ---------------- K2: consensus attention; recomputes S rows from tb in-block ----------------
__global__ __launch_bounds__(256) void k_attn(const float* __restrict__ tb,
    const float* __restrict__ sb,
    float4* __restrict__ accnP, float* __restrict__ accdP) {
  __shared__ float twi[262];
  __shared__ float twj[135];
  __shared__ __align__(16) float4 Sch[CH2];
  const int bx = blockIdx.x;
  const int jc = bx & (JC2 - 1);
  const int rt = (bx >> 5) % RT;
  const int b  = bx / (JC2 * RT);
  const int t = threadIdx.x;
  const int j0 = jc * CH2;
  const int i0 = rt * 256;
  const int rowb = b * N_;
  for (int idx = t; idx < 262; idx += 256) {
    const int j = i0 - 3 + idx;
    twi[idx] = (j >= 0 && j < N_) ? tb[rowb + j] : 0.f;
  }
  for (int idx = t; idx < 135; idx += 256) {
    const int j = j0 - 3 + idx;
    twj[idx] = (j >= 0 && j < N_) ? tb[rowb + j] : 0.f;
  }
  __syncthreads();
  const float bb = sb[0];
  if (t < CH2 && j0 + t < L_) Sch[t] = softmax4(twj, j0 - 3, j0 + t, bb);
  const int i = i0 + t;
  const float4 si = softmax4(twi, i0 - 3, i, bb);   // safe for i>=L_ (unused)
  __syncthreads();
  if (i < L_) {
    const int len = min(CH2, L_ - j0);
    float l = 0.f, a0 = 0.f, a1 = 0.f, a2 = 0.f, a3 = 0.f;
#pragma unroll 4
    for (int jj = 0; jj < len; ++jj) {
      const float4 v = Sch[jj];
      const float dot = fmaf(si.x, v.x, fmaf(si.y, v.y, fmaf(si.z, v.z, si.w * v.w)));
      const float e = __expf(dot);   // dot in (0,1]; no max-shift needed
      l += e;
      a0 = fmaf(e, v.x, a0); a1 = fmaf(e, v.y, a1);
      a2 = fmaf(e, v.z, a2); a3 = fmaf(e, v.w, a3);
    }
    const size_t base = (size_t)jc * (B_ * L_) + b * L_ + i;
    accnP[base] = make_float4(a0, a1, a2, a3);
    accdP[base] = l;
  }
}

// ---------------- K3: 12-row tiles: reduce attn partials -> wgt, pool h once, downsample ----------------
__global__ __launch_bounds__(256) void k_fuse(const __hip_bfloat16* __restrict__ h,
    const float4* __restrict__ accnP, const float* __restrict__ accdP,
    float* __restrict__ out) {
  __shared__ __align__(16) float4 wgtS[12];
  const int bx = blockIdx.x;
  const int b = bx / 342, j12 = bx % 342;
  const int t = threadIdx.x, d = t * 2;
  const int r0 = 12 * j12;

  if (t < 192) {
    const int r = t >> 4, q = t & 15;
    const size_t i1 = (size_t)q * (B_ * L_) + b * L_ + r0 + r;
    const size_t i2 = (size_t)(q + 16) * (B_ * L_) + b * L_ + r0 + r;
    float4 nv = accnP[i1];
    const float4 n2 = accnP[i2];
    nv.x += n2.x; nv.y += n2.y; nv.z += n2.z; nv.w += n2.w;
    float dv = accdP[i1] + accdP[i2];
#pragma unroll
    for (int m = 8; m >= 1; m >>= 1) {
      nv.x += __shfl_xor(nv.x, m); nv.y += __shfl_xor(nv.y, m);
      nv.z += __shfl_xor(nv.z, m); nv.w += __shfl_xor(nv.w, m);
      dv   += __shfl_xor(dv, m);
    }
    if (q == 0) {
      const float inv = 1.f / dv;
      wgtS[r] = make_float4(nv.x * inv, nv.y * inv, nv.z * inv, nv.w * inv);
    }
  }
  __syncthreads();

  const __hip_bfloat16* hb = h + (size_t)b * N_ * D_;
  float2 hv[12];
#pragma unroll
  for (int q = 0; q < 12; ++q) {
    const int row = r0 + q;
    if (row < N_) {
      const ushort2 u = *(const ushort2*)(hb + (size_t)row * D_ + d);
      hv[q] = make_float2(bf2f(u.x), bf2f(u.y));
    } else {
      hv[q] = make_float2(0.f, 0.f);
    }
  }

  float2 p2[6], p3[4], p4[3];
#pragma unroll
  for (int g = 0; g < 6; ++g) {
    p2[g].x = (hv[2 * g].x + hv[2 * g + 1].x) * 0.5f;
    p2[g].y = (hv[2 * g].y + hv[2 * g + 1].y) * 0.5f;
  }
#pragma unroll
  for (int g = 0; g < 4; ++g) {
    p3[g].x = (hv[3 * g].x + hv[3 * g + 1].x + hv[3 * g + 2].x) * (1.f / 3.f);
    p3[g].y = (hv[3 * g].y + hv[3 * g + 1].y + hv[3 * g + 2].y) * (1.f / 3.f);
  }
#pragma unroll
  for (int g = 0; g < 3; ++g) {
    p4[g].x = (hv[4 * g].x + hv[4 * g + 1].x + hv[4 * g + 2].x + hv[4 * g + 3].x) * 0.25f;
    p4[g].y = (hv[4 * g].y + hv[4 * g + 1].y + hv[4 * g + 2].y + hv[4 * g + 3].y) * 0.25f;
  }

#pragma unroll
  for (int o = 0; o < 3; ++o) {
    const int orow = j12 * 3 + o;
    if (orow < 1024) {
      float ox = 0.f, oy = 0.f;
#pragma unroll
      for (int rr = 0; rr < 4; ++rr) {
        const int r = 4 * o + rr;
        const float4 wv = wgtS[r];
        const float2 p1 = hv[r];
        const float2 q2 = p2[r >> 1];
        const float2 q3 = p3[r / 3];
        const float2 q4 = p4[o];
        ox += wv.x * p1.x + wv.y * q2.x + wv.z * q3.x + wv.w * q4.x;
        oy += wv.x * p1.y + wv.y * q2.y + wv.z * q3.y + wv.w * q4.y;
      }
      float2 ov; ov.x = ox * 0.25f; ov.y = oy * 0.25f;
      *(float2*)(out + (size_t)(b * 1024 + orow) * D_ + d) = ov;
    }
  }
}

extern "C" void kernel_launch(void* const* d_in, const int* in_sizes, int n_in,
                              void* d_out, int out_size, void* d_ws, size_t ws_size,
                              hipStream_t stream) {
  const int*   x       = (const int*)d_in[0];
  const float* emb     = (const float*)d_in[1];
  const float* conv_w  = (const float*)d_in[2];
  const float* conv_b  = (const float*)d_in[3];
  const float* proj_w  = (const float*)d_in[4];
  const float* proj_b  = (const float*)d_in[5];
  const float* score_w = (const float*)d_in[6];
  const float* score_b = (const float*)d_in[7];
  float* out = (float*)d_out;

  char* ws = (char*)d_ws;
  size_t off = 0;
  float*          G    = (float*)(ws + off);          off += (size_t)4 * 256 * 512 * 4;  // 2 MB
  float*          bias = (float*)(ws + off);          off += (size_t)512 * 4;
  __hip_bfloat16* h    = (__hip_bfloat16*)(ws + off); off += (size_t)16384 * 512 * 2;    // 16 MB
  float*          tb   = (float*)(ws + off);          off += (size_t)16384 * 4;
  float4*         accnP = (float4*)(ws + off);        off += (size_t)JC2 * B_ * L_ * 16; // 8.4 MB
  float*          accdP = (float*)(ws + off);         off += (size_t)JC2 * B_ * L_ * 4;  // 2.1 MB
  (void)in_sizes; (void)n_in; (void)out_size; (void)ws_size;

  k_g<<<34, 256, 0, stream>>>(emb, proj_w, conv_w, conv_b, proj_b, G, bias);
  k_h<<<2048, 256, 0, stream>>>(x, G, bias, score_w, (unsigned*)h, tb);
  k_attn<<<B_ * RT * JC2, 256, 0, stream>>>(tb, score_b, accnP, accdP);
  k_fuse<<<B_ * 342, 256, 0, stream>>>(h, accnP, accdP, out);
}

// Round 8
// 134.325 us; speedup vs baseline: 1.1109x; 1.1109x over previous
//
#include <hip/hip_runtime.h>
#include <hip/hip_bf16.h>

#define B_ 4
#define N_ 4096
#define L_ 4104
#define D_ 512
#define RT 17
#define JC2 32
#define CH2 129
#define BK 64

typedef __attribute__((ext_vector_type(8))) short bf16x8;
typedef __attribute__((ext_vector_type(4))) float f32x4;

__device__ __forceinline__ float bf2f(unsigned short u) {
  union { unsigned u; float f; } c; c.u = ((unsigned)u) << 16; return c.f;
}

// ---------------- K0: G_k = bf16(emb*cw_k) @ bf16(W)^T  + coalesced bias' ----------------
// G[k][tok][o], tok<256, o<512.
// Blocks 0..63: MFMA 64x128 tiles (4 m x 4 n x 4 taps). Blocks 64..127: bias', 8 outs each.
__global__ __launch_bounds__(256) void k_g(const float* __restrict__ emb,
    const float* __restrict__ pw, const float* __restrict__ cwp,
    const float* __restrict__ cb, const float* __restrict__ pb,
    float* __restrict__ G, float* __restrict__ biasp) {
  __shared__ __align__(16) __hip_bfloat16 As[2][64 * BK];
  __shared__ __align__(16) __hip_bfloat16 Bs[2][128 * BK];
  __shared__ __align__(16) float cwS[512];
  __shared__ float red[4];
  const int bx = blockIdx.x;
  const int t = threadIdx.x;
  const int w = t >> 6, l = t & 63;

  if (bx >= 64) {                        // bias'[o] = cb . W[o,:] + pb[o], coalesced by column
    const int o0 = (bx - 64) * 8;
    const float2 cv = *(const float2*)(cb + t * 2);
#pragma unroll
    for (int oo = 0; oo < 8; ++oo) {
      const int o = o0 + oo;
      const float2 wv = *(const float2*)(pw + (size_t)o * 512 + t * 2);
      float s = wv.x * cv.x + wv.y * cv.y;
#pragma unroll
      for (int off = 32; off > 0; off >>= 1) s += __shfl_xor(s, off);
      if (l == 0) red[w] = s;
      __syncthreads();
      if (t == 0) biasp[o] = red[0] + red[1] + red[2] + red[3] + pb[o];
      __syncthreads();
    }
    return;
  }

  const int m0 = (bx & 3) * 64;          // token tile
  const int n0 = ((bx >> 2) & 3) * 128;  // output-channel tile
  const int kp = bx >> 4;                // conv tap 0..3
  const int quad = l >> 4, r16 = l & 15;
  const int wc = w * 32;

  // cw for this tap -> LDS, once
  cwS[t]       = cwp[t * 4 + kp];
  cwS[t + 256] = cwp[(t + 256) * 4 + kp];

  f32x4 acc[4][2];
#pragma unroll
  for (int a = 0; a < 4; ++a)
#pragma unroll
    for (int bq = 0; bq < 2; ++bq) acc[a][bq] = (f32x4){0.f, 0.f, 0.f, 0.f};

  // staging (VALU): A rows 64 (4 thr/row, 2 granules each), B rows 128 (2 thr/row, 4 granules).
  // XOR granule swizzle (slot = g ^ (row&7)) matches fragment-read swizzle; reads 2-way-free.
  const int ra = t >> 2, ga0 = (t & 3) * 2;
  const int rb = t >> 1, gb0 = (t & 1) * 4;

#define STAGEG(buf, kb)                                                          \
  _Pragma("unroll")                                                              \
  for (int gi = 0; gi < 2; ++gi) {                                               \
    const int g = ga0 + gi;                                                      \
    const int c0 = (kb) + g * 8;                                                 \
    const float4 a0 = *(const float4*)(emb + (size_t)(m0 + ra) * 512 + c0);      \
    const float4 a1 = *(const float4*)(emb + (size_t)(m0 + ra) * 512 + c0 + 4);  \
    const float4 w0 = *(const float4*)(cwS + c0);                                \
    const float4 w1 = *(const float4*)(cwS + c0 + 4);                            \
    union { __hip_bfloat16 q[8]; bf16x8 v; } ua;                                 \
    ua.q[0] = __float2bfloat16(a0.x * w0.x); ua.q[1] = __float2bfloat16(a0.y * w0.y); \
    ua.q[2] = __float2bfloat16(a0.z * w0.z); ua.q[3] = __float2bfloat16(a0.w * w0.w); \
    ua.q[4] = __float2bfloat16(a1.x * w1.x); ua.q[5] = __float2bfloat16(a1.y * w1.y); \
    ua.q[6] = __float2bfloat16(a1.z * w1.z); ua.q[7] = __float2bfloat16(a1.w * w1.w); \
    *(bf16x8*)(&As[buf][ra * BK + ((g ^ (ra & 7)) * 8)]) = ua.v;                 \
  }                                                                              \
  _Pragma("unroll")                                                              \
  for (int gi = 0; gi < 4; ++gi) {                                               \
    const int g = gb0 + gi;                                                      \
    const int c0 = (kb) + g * 8;                                                 \
    const float4 b0 = *(const float4*)(pw + (size_t)(n0 + rb) * 512 + c0);       \
    const float4 b1 = *(const float4*)(pw + (size_t)(n0 + rb) * 512 + c0 + 4);   \
    union { __hip_bfloat16 q[8]; bf16x8 v; } ub;                                 \
    ub.q[0] = __float2bfloat16(b0.x); ub.q[1] = __float2bfloat16(b0.y);          \
    ub.q[2] = __float2bfloat16(b0.z); ub.q[3] = __float2bfloat16(b0.w);          \
    ub.q[4] = __float2bfloat16(b1.x); ub.q[5] = __float2bfloat16(b1.y);          \
    ub.q[6] = __float2bfloat16(b1.z); ub.q[7] = __float2bfloat16(b1.w);          \
    *(bf16x8*)(&Bs[buf][rb * BK + ((g ^ (rb & 7)) * 8)]) = ub.v;                 \
  }

  __syncthreads();        // cwS ready
  STAGEG(0, 0)
  __syncthreads();

#pragma unroll 1
  for (int kt = 0; kt < 8; ++kt) {
    const int cur = kt & 1;
    if (kt < 7) { STAGEG(1 - cur, (kt + 1) * BK) }
#pragma unroll
    for (int kk = 0; kk < 2; ++kk) {
      const int col_e = (kk * 32 + quad * 8) ^ ((r16 & 7) * 8);
      bf16x8 af[4], bfr[2];
#pragma unroll
      for (int ti = 0; ti < 4; ++ti)
        af[ti] = *(const bf16x8*)(&As[cur][(ti * 16 + r16) * BK + col_e]);
#pragma unroll
      for (int tj = 0; tj < 2; ++tj)
        bfr[tj] = *(const bf16x8*)(&Bs[cur][(wc + tj * 16 + r16) * BK + col_e]);
#pragma unroll
      for (int ti = 0; ti < 4; ++ti)
#pragma unroll
        for (int tj = 0; tj < 2; ++tj)
          acc[ti][tj] = __builtin_amdgcn_mfma_f32_16x16x32_bf16(af[ti], bfr[tj], acc[ti][tj], 0, 0, 0);
    }
    __syncthreads();
  }
#undef STAGEG

#pragma unroll
  for (int ti = 0; ti < 4; ++ti) {
    const int gi0 = m0 + ti * 16 + quad * 4;
#pragma unroll
    for (int tj = 0; tj < 2; ++tj) {
      const int go = n0 + wc + tj * 16 + r16;
#pragma unroll
      for (int r = 0; r < 4; ++r)
        G[((size_t)kp * 256 + gi0 + r) * 512 + go] = acc[ti][tj][r];
    }
  }
}

// ---------------- K1: h[i] = sum_k G_k[x[i+k]] + bias'  (bf16 out) + t = h . sw ----------
__global__ __launch_bounds__(256) void k_h(const int* __restrict__ x,
    const float* __restrict__ G, const float* __restrict__ biasp,
    const float* __restrict__ sw, unsigned* __restrict__ h,
    float* __restrict__ tb) {
  __shared__ int tokS[11];
  __shared__ float tpart[8][4];
  const int bx = blockIdx.x;             // 2048: b*512 + rowgroup
  const int b = bx >> 9, i0 = (bx & 511) * 8;
  const int t = threadIdx.x, d = t * 2, w = t >> 6, l = t & 63;
  if (t < 11) {
    const int j = i0 + t;
    tokS[t] = (j < N_) ? x[b * N_ + j] : 0;
  }
  __syncthreads();
  const float2 bp  = *(const float2*)(biasp + d);
  const float2 swv = *(const float2*)(sw + d);
#pragma unroll
  for (int r = 0; r < 8; ++r) {
    const int i = i0 + r;
    float2 acc = bp;
#pragma unroll
    for (int k = 0; k < 4; ++k) {
      if (i + k < N_) {
        const float2 g = *(const float2*)(G + ((size_t)k * 256 + tokS[r + k]) * 512 + d);
        acc.x += g.x; acc.y += g.y;
      }
    }
    union { __hip_bfloat16 q[2]; unsigned u; } pk;
    pk.q[0] = __float2bfloat16(acc.x);
    pk.q[1] = __float2bfloat16(acc.y);
    h[(size_t)(b * N_ + i) * 256 + t] = pk.u;
    float v = acc.x * swv.x + acc.y * swv.y;
#pragma unroll
    for (int off = 32; off > 0; off >>= 1) v += __shfl_xor(v, off);
    if (l == 0) tpart[r][w] = v;
  }
  __syncthreads();
  if (t < 8)
    tb[b * N_ + i0 + t] = tpart[t][0] + tpart[t][1] + tpart[t][2] + tpart[t][3];
}

// helper: 4-way softmax from a t-window in LDS
__device__ __forceinline__ float4 softmax4(const float* __restrict__ tw, int base,
                                           int i, float bb) {
  const float s0 = tw[i - base] + bb;
  const int j2 = i & ~1;
  const float s1 = (tw[j2 - base] + tw[j2 + 1 - base]) * 0.5f + bb;
  const int j3 = (i / 3) * 3;
  const float s2 = (tw[j3 - base] + tw[j3 + 1 - base] + tw[j3 + 2 - base]) * (1.f / 3.f) + bb;
  const int j4 = i & ~3;
  const float s3 = (tw[j4 - base] + tw[j4 + 1 - base] + tw[j4 + 2 - base] + tw[j4 + 3 - base]) * 0.25f + bb;
  const float m = fmaxf(fmaxf(s0, s1), fmaxf(s2, s3));
  const float e0 = __expf(s0 - m), e1 = __expf(s1 - m), e2 = __expf(s2 - m), e3 = __expf(s3 - m);
  const float inv = 1.f / (e0 + e1 + e2 + e3);
  return make_float4(e0 * inv, e1 * inv, e2 * inv, e3 * inv);
}

// ---------------- K2: consensus attention; recomputes S rows from tb in-block ----------------
__global__ __launch_bounds__(256) void k_attn(const float* __restrict__ tb,
    const float* __restrict__ sb,
    float4* __restrict__ accnP, float* __restrict__ accdP) {
  __shared__ float twi[262];
  __shared__ float twj[135];
  __shared__ __align__(16) float4 Sch[CH2];
  const int bx = blockIdx.x;
  const int jc = bx & (JC2 - 1);
  const int rt = (bx >> 5) % RT;
  const int b  = bx / (JC2 * RT);
  const int t = threadIdx.x;
  const int j0 = jc * CH2;
  const int i0 = rt * 256;
  const int rowb = b * N_;
  for (int idx = t; idx < 262; idx += 256) {
    const int j = i0 - 3 + idx;
    twi[idx] = (j >= 0 && j < N_) ? tb[rowb + j] : 0.f;
  }
  for (int idx = t; idx < 135; idx += 256) {
    const int j = j0 - 3 + idx;
    twj[idx] = (j >= 0 && j < N_) ? tb[rowb + j] : 0.f;
  }
  __syncthreads();
  const float bb = sb[0];
  if (t < CH2 && j0 + t < L_) Sch[t] = softmax4(twj, j0 - 3, j0 + t, bb);
  const int i = i0 + t;
  const float4 si = softmax4(twi, i0 - 3, i, bb);   // safe for i>=L_ (unused)
  __syncthreads();
  if (i < L_) {
    const int len = min(CH2, L_ - j0);
    float l = 0.f, a0 = 0.f, a1 = 0.f, a2 = 0.f, a3 = 0.f;
#pragma unroll 4
    for (int jj = 0; jj < len; ++jj) {
      const float4 v = Sch[jj];
      const float dot = fmaf(si.x, v.x, fmaf(si.y, v.y, fmaf(si.z, v.z, si.w * v.w)));
      const float e = __expf(dot);   // dot in (0,1]; no max-shift needed
      l += e;
      a0 = fmaf(e, v.x, a0); a1 = fmaf(e, v.y, a1);
      a2 = fmaf(e, v.z, a2); a3 = fmaf(e, v.w, a3);
    }
    const size_t base = (size_t)jc * (B_ * L_) + b * L_ + i;
    accnP[base] = make_float4(a0, a1, a2, a3);
    accdP[base] = l;
  }
}

// ---------------- K3: 12-row tiles: reduce attn partials -> wgt, pool h once, downsample ----------------
__global__ __launch_bounds__(256) void k_fuse(const __hip_bfloat16* __restrict__ h,
    const float4* __restrict__ accnP, const float* __restrict__ accdP,
    float* __restrict__ out) {
  __shared__ __align__(16) float4 wgtS[12];
  const int bx = blockIdx.x;
  const int b = bx / 342, j12 = bx % 342;
  const int t = threadIdx.x, d = t * 2;
  const int r0 = 12 * j12;

  if (t < 192) {
    const int r = t >> 4, q = t & 15;
    const size_t i1 = (size_t)q * (B_ * L_) + b * L_ + r0 + r;
    const size_t i2 = (size_t)(q + 16) * (B_ * L_) + b * L_ + r0 + r;
    float4 nv = accnP[i1];
    const float4 n2 = accnP[i2];
    nv.x += n2.x; nv.y += n2.y; nv.z += n2.z; nv.w += n2.w;
    float dv = accdP[i1] + accdP[i2];
#pragma unroll
    for (int m = 8; m >= 1; m >>= 1) {
      nv.x += __shfl_xor(nv.x, m); nv.y += __shfl_xor(nv.y, m);
      nv.z += __shfl_xor(nv.z, m); nv.w += __shfl_xor(nv.w, m);
      dv   += __shfl_xor(dv, m);
    }
    if (q == 0) {
      const float inv = 1.f / dv;
      wgtS[r] = make_float4(nv.x * inv, nv.y * inv, nv.z * inv, nv.w * inv);
    }
  }
  __syncthreads();

  const __hip_bfloat16* hb = h + (size_t)b * N_ * D_;
  float2 hv[12];
#pragma unroll
  for (int q = 0; q < 12; ++q) {
    const int row = r0 + q;
    if (row < N_) {
      const ushort2 u = *(const ushort2*)(hb + (size_t)row * D_ + d);
      hv[q] = make_float2(bf2f(u.x), bf2f(u.y));
    } else {
      hv[q] = make_float2(0.f, 0.f);
    }
  }

  float2 p2[6], p3[4], p4[3];
#pragma unroll
  for (int g = 0; g < 6; ++g) {
    p2[g].x = (hv[2 * g].x + hv[2 * g + 1].x) * 0.5f;
    p2[g].y = (hv[2 * g].y + hv[2 * g + 1].y) * 0.5f;
  }
#pragma unroll
  for (int g = 0; g < 4; ++g) {
    p3[g].x = (hv[3 * g].x + hv[3 * g + 1].x + hv[3 * g + 2].x) * (1.f / 3.f);
    p3[g].y = (hv[3 * g].y + hv[3 * g + 1].y + hv[3 * g + 2].y) * (1.f / 3.f);
  }
#pragma unroll
  for (int g = 0; g < 3; ++g) {
    p4[g].x = (hv[4 * g].x + hv[4 * g + 1].x + hv[4 * g + 2].x + hv[4 * g + 3].x) * 0.25f;
    p4[g].y = (hv[4 * g].y + hv[4 * g + 1].y + hv[4 * g + 2].y + hv[4 * g + 3].y) * 0.25f;
  }

#pragma unroll
  for (int o = 0; o < 3; ++o) {
    const int orow = j12 * 3 + o;
    if (orow < 1024) {
      float ox = 0.f, oy = 0.f;
#pragma unroll
      for (int rr = 0; rr < 4; ++rr) {
        const int r = 4 * o + rr;
        const float4 wv = wgtS[r];
        const float2 p1 = hv[r];
        const float2 q2 = p2[r >> 1];
        const float2 q3 = p3[r / 3];
        const float2 q4 = p4[o];
        ox += wv.x * p1.x + wv.y * q2.x + wv.z * q3.x + wv.w * q4.x;
        oy += wv.x * p1.y + wv.y * q2.y + wv.z * q3.y + wv.w * q4.y;
      }
      float2 ov; ov.x = ox * 0.25f; ov.y = oy * 0.25f;
      *(float2*)(out + (size_t)(b * 1024 + orow) * D_ + d) = ov;
    }
  }
}

extern "C" void kernel_launch(void* const* d_in, const int* in_sizes, int n_in,
                              void* d_out, int out_size, void* d_ws, size_t ws_size,
                              hipStream_t stream) {
  const int*   x       = (const int*)d_in[0];
  const float* emb     = (const float*)d_in[1];
  const float* conv_w  = (const float*)d_in[2];
  const float* conv_b  = (const float*)d_in[3];
  const float* proj_w  = (const float*)d_in[4];
  const float* proj_b  = (const float*)d_in[5];
  const float* score_w = (const float*)d_in[6];
  const float* score_b = (const float*)d_in[7];
  float* out = (float*)d_out;

  char* ws = (char*)d_ws;
  size_t off = 0;
  float*          G    = (float*)(ws + off);          off += (size_t)4 * 256 * 512 * 4;  // 2 MB
  float*          bias = (float*)(ws + off);          off += (size_t)512 * 4;
  __hip_bfloat16* h    = (__hip_bfloat16*)(ws + off); off += (size_t)16384 * 512 * 2;    // 16 MB
  float*          tb   = (float*)(ws + off);          off += (size_t)16384 * 4;
  float4*         accnP = (float4*)(ws + off);        off += (size_t)JC2 * B_ * L_ * 16; // 8.4 MB
  float*          accdP = (float*)(ws + off);         off += (size_t)JC2 * B_ * L_ * 4;  // 2.1 MB
  (void)in_sizes; (void)n_in; (void)out_size; (void)ws_size;

  k_g<<<128, 256, 0, stream>>>(emb, proj_w, conv_w, conv_b, proj_b, G, bias);
  k_h<<<2048, 256, 0, stream>>>(x, G, bias, score_w, (unsigned*)h, tb);
  k_attn<<<B_ * RT * JC2, 256, 0, stream>>>(tb, score_b, accnP, accdP);
  k_fuse<<<B_ * 342, 256, 0, stream>>>(h, accnP, accdP, out);
}

// Round 9
// 126.450 us; speedup vs baseline: 1.1801x; 1.0623x over previous
//
#include <hip/hip_runtime.h>
#include <hip/hip_bf16.h>

#define B_ 4
#define N_ 4096
#define L_ 4104
#define D_ 512
#define CH2 129
#define BK 64
#define NF 210     // monomials of degree <=6 in 4 vars

typedef __attribute__((ext_vector_type(8))) short bf16x8;
typedef __attribute__((ext_vector_type(4))) float f32x4;

__device__ __forceinline__ float bf2f(unsigned short u) {
  union { unsigned u; float f; } c; c.u = ((unsigned)u) << 16; return c.f;
}

// ---------------- K0: G_k = bf16(emb*cw_k) @ bf16(W)^T + bias' + feature table --------
__global__ __launch_bounds__(256) void k_g(const float* __restrict__ emb,
    const float* __restrict__ pw, const float* __restrict__ cwp,
    const float* __restrict__ cb, const float* __restrict__ pb,
    float* __restrict__ G, float* __restrict__ biasp,
    unsigned* __restrict__ featPk, float* __restrict__ featCf) {
  __shared__ __align__(16) __hip_bfloat16 As[2][64 * BK];
  __shared__ __align__(16) __hip_bfloat16 Bs[2][128 * BK];
  __shared__ __align__(16) float cwS[512];
  __shared__ float red[4];
  const int bx = blockIdx.x;
  const int t = threadIdx.x;
  const int w = t >> 6, l = t & 63;

  if (bx == 128) {                       // build Taylor feature table (uniform loop, no divergence)
    if (t < NF) {
      int idx = 0, mp = 0, mq = 0, mr = 0, ms = 0;
      for (int m = 0; m <= 6; ++m)
        for (int p = m; p >= 0; --p)
          for (int q = m - p; q >= 0; --q)
            for (int r = m - p - q; r >= 0; --r) {
              const int s4 = m - p - q - r;
              if (idx == t) { mp = p; mq = q; mr = r; ms = s4; }
              ++idx;
            }
      featPk[t] = (unsigned)mp | ((unsigned)mq << 8) | ((unsigned)mr << 16) | ((unsigned)ms << 24);
      const float invf[7] = {1.f, 1.f, 0.5f, 1.f/6.f, 1.f/24.f, 1.f/120.f, 1.f/720.f};
      featCf[t] = invf[mp] * invf[mq] * invf[mr] * invf[ms];
    }
    return;
  }
  if (bx >= 64) {                        // bias'[o] = cb . W[o,:] + pb[o], coalesced by column
    const int o0 = (bx - 64) * 8;
    const float2 cv = *(const float2*)(cb + t * 2);
#pragma unroll
    for (int oo = 0; oo < 8; ++oo) {
      const int o = o0 + oo;
      const float2 wv = *(const float2*)(pw + (size_t)o * 512 + t * 2);
      float s = wv.x * cv.x + wv.y * cv.y;
#pragma unroll
      for (int off = 32; off > 0; off >>= 1) s += __shfl_xor(s, off);
      if (l == 0) red[w] = s;
      __syncthreads();
      if (t == 0) biasp[o] = red[0] + red[1] + red[2] + red[3] + pb[o];
      __syncthreads();
    }
    return;
  }

  const int m0 = (bx & 3) * 64;          // token tile
  const int n0 = ((bx >> 2) & 3) * 128;  // output-channel tile
  const int kp = bx >> 4;                // conv tap 0..3
  const int quad = l >> 4, r16 = l & 15;
  const int wc = w * 32;

  cwS[t]       = cwp[t * 4 + kp];
  cwS[t + 256] = cwp[(t + 256) * 4 + kp];

  f32x4 acc[4][2];
#pragma unroll
  for (int a = 0; a < 4; ++a)
#pragma unroll
    for (int bq = 0; bq < 2; ++bq) acc[a][bq] = (f32x4){0.f, 0.f, 0.f, 0.f};

  const int ra = t >> 2, ga0 = (t & 3) * 2;
  const int rb = t >> 1, gb0 = (t & 1) * 4;

#define STAGEG(buf, kb)                                                          \
  _Pragma("unroll")                                                              \
  for (int gi = 0; gi < 2; ++gi) {                                               \
    const int g = ga0 + gi;                                                      \
    const int c0 = (kb) + g * 8;                                                 \
    const float4 a0 = *(const float4*)(emb + (size_t)(m0 + ra) * 512 + c0);      \
    const float4 a1 = *(const float4*)(emb + (size_t)(m0 + ra) * 512 + c0 + 4);  \
    const float4 w0 = *(const float4*)(cwS + c0);                                \
    const float4 w1 = *(const float4*)(cwS + c0 + 4);                            \
    union { __hip_bfloat16 q[8]; bf16x8 v; } ua;                                 \
    ua.q[0] = __float2bfloat16(a0.x * w0.x); ua.q[1] = __float2bfloat16(a0.y * w0.y); \
    ua.q[2] = __float2bfloat16(a0.z * w0.z); ua.q[3] = __float2bfloat16(a0.w * w0.w); \
    ua.q[4] = __float2bfloat16(a1.x * w1.x); ua.q[5] = __float2bfloat16(a1.y * w1.y); \
    ua.q[6] = __float2bfloat16(a1.z * w1.z); ua.q[7] = __float2bfloat16(a1.w * w1.w); \
    *(bf16x8*)(&As[buf][ra * BK + ((g ^ (ra & 7)) * 8)]) = ua.v;                 \
  }                                                                              \
  _Pragma("unroll")                                                              \
  for (int gi = 0; gi < 4; ++gi) {                                               \
    const int g = gb0 + gi;                                                      \
    const int c0 = (kb) + g * 8;                                                 \
    const float4 b0 = *(const float4*)(pw + (size_t)(n0 + rb) * 512 + c0);       \
    const float4 b1 = *(const float4*)(pw + (size_t)(n0 + rb) * 512 + c0 + 4);   \
    union { __hip_bfloat16 q[8]; bf16x8 v; } ub;                                 \
    ub.q[0] = __float2bfloat16(b0.x); ub.q[1] = __float2bfloat16(b0.y);          \
    ub.q[2] = __float2bfloat16(b0.z); ub.q[3] = __float2bfloat16(b0.w);          \
    ub.q[4] = __float2bfloat16(b1.x); ub.q[5] = __float2bfloat16(b1.y);          \
    ub.q[6] = __float2bfloat16(b1.z); ub.q[7] = __float2bfloat16(b1.w);          \
    *(bf16x8*)(&Bs[buf][rb * BK + ((g ^ (rb & 7)) * 8)]) = ub.v;                 \
  }

  __syncthreads();        // cwS ready
  STAGEG(0, 0)
  __syncthreads();

#pragma unroll 1
  for (int kt = 0; kt < 8; ++kt) {
    const int cur = kt & 1;
    if (kt < 7) { STAGEG(1 - cur, (kt + 1) * BK) }
#pragma unroll
    for (int kk = 0; kk < 2; ++kk) {
      const int col_e = (kk * 32 + quad * 8) ^ ((r16 & 7) * 8);
      bf16x8 af[4], bfr[2];
#pragma unroll
      for (int ti = 0; ti < 4; ++ti)
        af[ti] = *(const bf16x8*)(&As[cur][(ti * 16 + r16) * BK + col_e]);
#pragma unroll
      for (int tj = 0; tj < 2; ++tj)
        bfr[tj] = *(const bf16x8*)(&Bs[cur][(wc + tj * 16 + r16) * BK + col_e]);
#pragma unroll
      for (int ti = 0; ti < 4; ++ti)
#pragma unroll
        for (int tj = 0; tj < 2; ++tj)
          acc[ti][tj] = __builtin_amdgcn_mfma_f32_16x16x32_bf16(af[ti], bfr[tj], acc[ti][tj], 0, 0, 0);
    }
    __syncthreads();
  }
#undef STAGEG

#pragma unroll
  for (int ti = 0; ti < 4; ++ti) {
    const int gi0 = m0 + ti * 16 + quad * 4;
#pragma unroll
    for (int tj = 0; tj < 2; ++tj) {
      const int go = n0 + wc + tj * 16 + r16;
#pragma unroll
      for (int r = 0; r < 4; ++r)
        G[((size_t)kp * 256 + gi0 + r) * 512 + go] = acc[ti][tj][r];
    }
  }
}

// ---------------- K1: h[i] = sum_k G_k[x[i+k]] + bias' (bf16) + t = h.sw + zero Z ------
__global__ __launch_bounds__(256) void k_h(const int* __restrict__ x,
    const float* __restrict__ G, const float* __restrict__ biasp,
    const float* __restrict__ sw, unsigned* __restrict__ h,
    float* __restrict__ tb, float* __restrict__ Zg) {
  __shared__ int tokS[11];
  __shared__ float tpart[8][4];
  const int bx = blockIdx.x;             // 2048: b*512 + rowgroup
  const int b = bx >> 9, i0 = (bx & 511) * 8;
  const int t = threadIdx.x, d = t * 2, w = t >> 6, l = t & 63;
  if (bx < 17) {                         // zero the 4*NF*5 moment buffer
    const int zi = bx * 256 + t;
    if (zi < B_ * NF * 5) Zg[zi] = 0.f;
  }
  if (t < 11) {
    const int j = i0 + t;
    tokS[t] = (j < N_) ? x[b * N_ + j] : 0;
  }
  __syncthreads();
  const float2 bp  = *(const float2*)(biasp + d);
  const float2 swv = *(const float2*)(sw + d);
#pragma unroll
  for (int r = 0; r < 8; ++r) {
    const int i = i0 + r;
    float2 acc = bp;
#pragma unroll
    for (int k = 0; k < 4; ++k) {
      if (i + k < N_) {
        const float2 g = *(const float2*)(G + ((size_t)k * 256 + tokS[r + k]) * 512 + d);
        acc.x += g.x; acc.y += g.y;
      }
    }
    union { __hip_bfloat16 q[2]; unsigned u; } pk;
    pk.q[0] = __float2bfloat16(acc.x);
    pk.q[1] = __float2bfloat16(acc.y);
    h[(size_t)(b * N_ + i) * 256 + t] = pk.u;
    float v = acc.x * swv.x + acc.y * swv.y;
#pragma unroll
    for (int off = 32; off > 0; off >>= 1) v += __shfl_xor(v, off);
    if (l == 0) tpart[r][w] = v;
  }
  __syncthreads();
  if (t < 8)
    tb[b * N_ + i0 + t] = tpart[t][0] + tpart[t][1] + tpart[t][2] + tpart[t][3];
}

// helper: 4-way softmax from a t-window in LDS
__device__ __forceinline__ float4 softmax4(const float* __restrict__ tw, int base,
                                           int i, float bb) {
  const float s0 = tw[i - base] + bb;
  const int j2 = i & ~1;
  const float s1 = (tw[j2 - base] + tw[j2 + 1 - base]) * 0.5f + bb;
  const int j3 = (i / 3) * 3;
  const float s2 = (tw[j3 - base] + tw[j3 + 1 - base] + tw[j3 + 2 - base]) * (1.f / 3.f) + bb;
  const int j4 = i & ~3;
  const float s3 = (tw[j4 - base] + tw[j4 + 1 - base] + tw[j4 + 2 - base] + tw[j4 + 3 - base]) * 0.25f + bb;
  const float m = fmaxf(fmaxf(s0, s1), fmaxf(s2, s3));
  const float e0 = __expf(s0 - m), e1 = __expf(s1 - m), e2 = __expf(s2 - m), e3 = __expf(s3 - m);
  const float inv = 1.f / (e0 + e1 + e2 + e3);
  return make_float4(e0 * inv, e1 * inv, e2 * inv, e3 * inv);
}

// ---------------- K2: j-side moments  Z[alpha] = sum_j s_j^alpha * [s_j;1] -------------
__global__ __launch_bounds__(256) void k_zphi(const float* __restrict__ tb,
    const float* __restrict__ sb, const unsigned* __restrict__ featPk,
    const float* __restrict__ featCf, float* __restrict__ Zg) {
  __shared__ float twj[135];
  __shared__ float P[CH2][32];           // powers 0..7 of each of 4 components per j
  __shared__ unsigned pkS[NF];
  const int bx = blockIdx.x;             // 128: b*32 + jc
  const int b = bx >> 5, jc = bx & 31;
  const int t = threadIdx.x;
  const int j0 = jc * CH2;
  const int rowb = b * N_;
  const int len = min(CH2, L_ - j0);
  if (t < NF) pkS[t] = featPk[t];
  for (int idx = t; idx < 135; idx += 256) {
    const int j = j0 - 3 + idx;
    twj[idx] = (j >= 0 && j < N_) ? tb[rowb + j] : 0.f;
  }
  __syncthreads();
  const float bb = sb[0];
  if (t < len) {
    const float4 s = softmax4(twj, j0 - 3, j0 + t, bb);
    float* p = &P[t][0];
    float va = 1.f, vb = 1.f, vc = 1.f, vd = 1.f;
    p[0] = 1.f; p[8] = 1.f; p[16] = 1.f; p[24] = 1.f;
#pragma unroll
    for (int e = 1; e < 8; ++e) {
      va *= s.x; vb *= s.y; vc *= s.z; vd *= s.w;
      p[e] = va; p[8 + e] = vb; p[16 + e] = vc; p[24 + e] = vd;
    }
  }
  __syncthreads();
  if (t < NF) {
    const unsigned pk = pkS[t];
    const int p = pk & 255, q = (pk >> 8) & 255, r = (pk >> 16) & 255, s4 = pk >> 24;
    float z0 = 0.f, z1 = 0.f, z2 = 0.f, z3 = 0.f, z4 = 0.f;
    for (int jj = 0; jj < len; ++jj) {
      const float* pp = &P[jj][0];
      const float pa0 = pp[p],       pa1 = pp[p + 1];
      const float pb0 = pp[8 + q],   pb1 = pp[8 + q + 1];
      const float pc0 = pp[16 + r],  pc1 = pp[16 + r + 1];
      const float pd0 = pp[24 + s4], pd1 = pp[24 + s4 + 1];
      const float cd = pc0 * pd0, ab = pa0 * pb0;
      z4 += pa0 * (pb0 * cd);
      z0 += pa1 * (pb0 * cd);
      z1 += pb1 * (pa0 * cd);
      z2 += pc1 * (ab * pd0);
      z3 += pd1 * (ab * pc0);
    }
    float* zb = Zg + (size_t)(b * NF + t) * 5;
    atomicAdd(zb + 0, z0); atomicAdd(zb + 1, z1); atomicAdd(zb + 2, z2);
    atomicAdd(zb + 3, z3); atomicAdd(zb + 4, z4);
  }
}

// ---------------- K3: 12-row tiles: wgt from phi(s_i).Z, pool h once, downsample -------
__global__ __launch_bounds__(256) void k_fuse(const __hip_bfloat16* __restrict__ h,
    const float* __restrict__ tb, const float* __restrict__ sb,
    const unsigned* __restrict__ featPk, const float* __restrict__ featCf,
    const float* __restrict__ Zg, float* __restrict__ out) {
  __shared__ __align__(16) float4 wgtS[12];
  __shared__ float tbS[12];
  __shared__ float Pr[12][32];
  __shared__ float Zl[NF * 5];
  __shared__ unsigned pkS[NF];
  __shared__ float cfS[NF];
  const int bx = blockIdx.x;
  const int b = bx / 342, j12 = bx % 342;
  const int t = threadIdx.x, d = t * 2;
  const int r0 = 12 * j12;

  if (t < NF) { pkS[t] = featPk[t]; cfS[t] = featCf[t]; }
  for (int i2 = t; i2 < NF * 5; i2 += 256) Zl[i2] = Zg[(size_t)b * NF * 5 + i2];
  if (t < 12) {
    const int row = r0 + t;
    tbS[t] = (row < N_) ? tb[b * N_ + row] : 0.f;
  }
  __syncthreads();
  if (t < 12) {                          // powers of s_i for this tile's 12 rows
    const float4 s = softmax4(tbS, r0, r0 + t, sb[0]);
    float* p = &Pr[t][0];
    float va = 1.f, vb = 1.f, vc = 1.f, vd = 1.f;
    p[0] = 1.f; p[8] = 1.f; p[16] = 1.f; p[24] = 1.f;
#pragma unroll
    for (int e = 1; e < 8; ++e) {
      va *= s.x; vb *= s.y; vc *= s.z; vd *= s.w;
      p[e] = va; p[8 + e] = vb; p[16 + e] = vc; p[24 + e] = vd;
    }
  }
  __syncthreads();
  if (t < 192) {                         // 16 lanes per row evaluate phi . Z
    const int row = t >> 4, fi = t & 15;
    float n0 = 0.f, n1 = 0.f, n2 = 0.f, n3 = 0.f, dn = 0.f;
    const float* pr = &Pr[row][0];
    for (int f = fi; f < NF; f += 16) {
      const unsigned pk = pkS[f];
      const float val = cfS[f] * pr[pk & 255] * pr[8 + ((pk >> 8) & 255)]
                                * pr[16 + ((pk >> 16) & 255)] * pr[24 + (pk >> 24)];
      const float* z = &Zl[f * 5];
      n0 += val * z[0]; n1 += val * z[1]; n2 += val * z[2]; n3 += val * z[3];
      dn += val * z[4];
    }
#pragma unroll
    for (int m = 8; m >= 1; m >>= 1) {
      n0 += __shfl_xor(n0, m); n1 += __shfl_xor(n1, m); n2 += __shfl_xor(n2, m);
      n3 += __shfl_xor(n3, m); dn += __shfl_xor(dn, m);
    }
    if (fi == 0) {
      const float inv = 1.f / dn;
      wgtS[row] = make_float4(n0 * inv, n1 * inv, n2 * inv, n3 * inv);
    }
  }
  __syncthreads();

  const __hip_bfloat16* hb = h + (size_t)b * N_ * D_;
  float2 hv[12];
#pragma unroll
  for (int q = 0; q < 12; ++q) {
    const int row = r0 + q;
    if (row < N_) {
      const ushort2 u = *(const ushort2*)(hb + (size_t)row * D_ + d);
      hv[q] = make_float2(bf2f(u.x), bf2f(u.y));
    } else {
      hv[q] = make_float2(0.f, 0.f);
    }
  }

  float2 p2[6], p3[4], p4[3];
#pragma unroll
  for (int g = 0; g < 6; ++g) {
    p2[g].x = (hv[2 * g].x + hv[2 * g + 1].x) * 0.5f;
    p2[g].y = (hv[2 * g].y + hv[2 * g + 1].y) * 0.5f;
  }
#pragma unroll
  for (int g = 0; g < 4; ++g) {
    p3[g].x = (hv[3 * g].x + hv[3 * g + 1].x + hv[3 * g + 2].x) * (1.f / 3.f);
    p3[g].y = (hv[3 * g].y + hv[3 * g + 1].y + hv[3 * g + 2].y) * (1.f / 3.f);
  }
#pragma unroll
  for (int g = 0; g < 3; ++g) {
    p4[g].x = (hv[4 * g].x + hv[4 * g + 1].x + hv[4 * g + 2].x + hv[4 * g + 3].x) * 0.25f;
    p4[g].y = (hv[4 * g].y + hv[4 * g + 1].y + hv[4 * g + 2].y + hv[4 * g + 3].y) * 0.25f;
  }

#pragma unroll
  for (int o = 0; o < 3; ++o) {
    const int orow = j12 * 3 + o;
    if (orow < 1024) {
      float ox = 0.f, oy = 0.f;
#pragma unroll
      for (int rr = 0; rr < 4; ++rr) {
        const int r = 4 * o + rr;
        const float4 wv = wgtS[r];
        const float2 p1 = hv[r];
        const float2 q2 = p2[r >> 1];
        const float2 q3 = p3[r / 3];
        const float2 q4 = p4[o];
        ox += wv.x * p1.x + wv.y * q2.x + wv.z * q3.x + wv.w * q4.x;
        oy += wv.x * p1.y + wv.y * q2.y + wv.z * q3.y + wv.w * q4.y;
      }
      float2 ov; ov.x = ox * 0.25f; ov.y = oy * 0.25f;
      *(float2*)(out + (size_t)(b * 1024 + orow) * D_ + d) = ov;
    }
  }
}

extern "C" void kernel_launch(void* const* d_in, const int* in_sizes, int n_in,
                              void* d_out, int out_size, void* d_ws, size_t ws_size,
                              hipStream_t stream) {
  const int*   x       = (const int*)d_in[0];
  const float* emb     = (const float*)d_in[1];
  const float* conv_w  = (const float*)d_in[2];
  const float* conv_b  = (const float*)d_in[3];
  const float* proj_w  = (const float*)d_in[4];
  const float* proj_b  = (const float*)d_in[5];
  const float* score_w = (const float*)d_in[6];
  const float* score_b = (const float*)d_in[7];
  float* out = (float*)d_out;

  char* ws = (char*)d_ws;
  size_t off = 0;
  float*          G    = (float*)(ws + off);          off += (size_t)4 * 256 * 512 * 4;  // 2 MB
  float*          bias = (float*)(ws + off);          off += (size_t)512 * 4;
  __hip_bfloat16* h    = (__hip_bfloat16*)(ws + off); off += (size_t)16384 * 512 * 2;    // 16 MB
  float*          tb   = (float*)(ws + off);          off += (size_t)16384 * 4;
  float*          Zg   = (float*)(ws + off);          off += (size_t)B_ * NF * 5 * 4;
  unsigned*       featPk = (unsigned*)(ws + off);     off += (size_t)NF * 4;
  float*          featCf = (float*)(ws + off);        off += (size_t)NF * 4;
  (void)in_sizes; (void)n_in; (void)out_size; (void)ws_size;

  k_g<<<129, 256, 0, stream>>>(emb, proj_w, conv_w, conv_b, proj_b, G, bias, featPk, featCf);
  k_h<<<2048, 256, 0, stream>>>(x, G, bias, score_w, (unsigned*)h, tb, Zg);
  k_zphi<<<B_ * 32, 256, 0, stream>>>(tb, score_b, featPk, featCf, Zg);
  k_fuse<<<B_ * 342, 256, 0, stream>>>(h, tb, score_b, featPk, featCf, Zg, out);
}